// Round 11
// baseline (152.511 us; speedup 1.0000x reference)
//
#include <hip/hip_runtime.h>

// ECConv: out = relu(concat(nf[:8192], mean_seg(relu(EF@We+be).reshape(E,64,64) @ h_src)) @ Wn + bn)
// Sizes: E=65536, N_SRC=32768, N_DST=8192, EDGE_IN=32, NODE_IN=64, HIDDEN=64
// R11: ABLATION ROUND. Facts: 48-54us edge time invariant to occupancy (10-45%), VALU packing,
//      global-vs-LDS B sourcing (R10: zero hot-loop global loads, no spills -> 54us). Static
//      budgets say ~16-20us. This round measures WHERE the 48us lives: edge_ablate = edge5's
//      exact loop minus the VALU epilogue (MFMA C-chained accumulation, loads kept live via
//      asm keep-alives), grid x4 for top-5 visibility; phase time = dur/4.
//      Branch plan: dur/4 ~12-18 -> epilogue/hazard is the cost -> pipeline epilogue behind
//      MFMAs next. dur/4 ~35-45 -> MFMA+load loop is the cost -> 32x32x16 shape next.
// Lessons: R2 fp32 atomics memory-side. R4 serial scan 20us. R5/R9 long-lived staging regs
//      spill (WRITE >> payload is the tell). R6 sequential dispatches don't stack. R10 zero
//      global loads != faster -> load-serialization theory dead.

typedef float f32x4 __attribute__((ext_vector_type(4)));
typedef float f32x2 __attribute__((ext_vector_type(2)));
typedef __bf16 bf16x8 __attribute__((ext_vector_type(8)));
typedef __bf16 bf16x4 __attribute__((ext_vector_type(4)));

#define E_TOT   65536
#define NDST    8192
#define EPW     72    // bf16 hs pad (atomic-fallback kernel)
#define EPF     68    // f32 hs pad (fast kernel)

// ---- prep: pack We (fp32 [32][4096]) -> MFMA-B fragment order bf16 + bias tiles ----
// Tile T = d0*4 + ht covers GEMM cols n = (ht*16 + c)*64 + d0, c=0..15.
// B frag for mfma_f32_16x16x32_bf16: lane l holds B[k=(l>>4)*8+j][col=l&15], j=0..7.
__global__ __launch_bounds__(256) void prep_kernel(
    const float* __restrict__ We, const float* __restrict__ be,
    __bf16* __restrict__ Wp, float* __restrict__ bp) {
  int tid = blockIdx.x * 256 + threadIdx.x;       // 16384 packers
  int T = tid >> 6, l = tid & 63;
  int d0 = T >> 2, ht = T & 3;
  int c = l & 15, kg = l >> 4;
  int ncol = (ht * 16 + c) * 64 + d0;
  bf16x8 v;
#pragma unroll
  for (int j = 0; j < 8; ++j) v[j] = (__bf16)We[(kg * 8 + j) * 4096 + ncol];
  *reinterpret_cast<bf16x8*>(Wp + tid * 8) = v;
  if (l < 16) bp[T * 16 + l] = be[(ht * 16 + l) * 64 + d0];
}

// ---- parallel exclusive scan over 8192 bins (one block, shfl + LDS) ----
__global__ __launch_bounds__(256) void scan_kernel(const int* __restrict__ cnt_i,
                                                   int* __restrict__ off,
                                                   int* __restrict__ cursor) {
  __shared__ int wsum[4];
  const int t = threadIdx.x;
  const int lane = t & 63, w = t >> 6;
  int vals[32];
  const int4* cp = (const int4*)(cnt_i + t * 32);
#pragma unroll
  for (int i = 0; i < 8; ++i) {
    int4 v = cp[i];
    vals[i * 4 + 0] = v.x; vals[i * 4 + 1] = v.y;
    vals[i * 4 + 2] = v.z; vals[i * 4 + 3] = v.w;
  }
  int loc[32];
  int s = 0;
#pragma unroll
  for (int i = 0; i < 32; ++i) { loc[i] = s; s += vals[i]; }
  int inc = s;
#pragma unroll
  for (int d = 1; d < 64; d <<= 1) {
    int n = __shfl_up(inc, d, 64);
    if (lane >= d) inc += n;
  }
  if (lane == 63) wsum[w] = inc;
  __syncthreads();
  int base = inc - s;
#pragma unroll
  for (int i = 0; i < 4; ++i)
    if (i < w) base += wsum[i];
#pragma unroll
  for (int i = 0; i < 32; ++i) {
    int v = base + loc[i];
    off[t * 32 + i] = v;
    cursor[t * 32 + i] = v;
  }
  if (t == 255) off[8192] = E_TOT;
}

// ---- fill: scatter edge ids into CSR order (int atomics on cursor) ----
__global__ void fill_kernel(const int* __restrict__ dst, int* __restrict__ cursor,
                            int* __restrict__ eid) {
  int e = blockIdx.x * 256 + threadIdx.x;
  int slot = atomicAdd(&cursor[dst[e]], 1);
  eid[slot] = e;
}

// ---- ABLATION: edge5's exact loop, VALU epilogue removed (MFMA C-chained acc) ----
// grid 4096 (x4 work, bid&1023 selects edge block); only bid<1024 stores (into m,
// later overwritten by the real edge5). hvf/bv loads kept live via asm keep-alives.
__global__ __launch_bounds__(256, 2) void edge_ablate_kernel(
    const float* __restrict__ nf, const float* __restrict__ ef,
    const int* __restrict__ src, const __bf16* __restrict__ Wp,
    const float* __restrict__ bp, float* __restrict__ m) {
  __shared__ float hs[64 * EPF];
  const int t = threadIdx.x;
  const int eblk = (blockIdx.x & 1023) << 6;

  {
    const int el = t & 63, q = t >> 6;
    const int srow = src[eblk + el];
    const f32x4* nfr = (const f32x4*)(nf + (srow << 6) + (q << 4));
#pragma unroll
    for (int i = 0; i < 4; ++i) {
      f32x4 v = nfr[i];
      const int dbase = (q << 4) + i * 4;
      hs[(dbase + 0) * EPF + el] = v[0];
      hs[(dbase + 1) * EPF + el] = v[1];
      hs[(dbase + 2) * EPF + el] = v[2];
      hs[(dbase + 3) * EPF + el] = v[3];
    }
  }

  const int w = t >> 6, l = t & 63;
  const int c = l & 15, g = l >> 4;

  bf16x8 afr[4];
#pragma unroll
  for (int as = 0; as < 4; ++as) {
    const int e = eblk + as * 16 + c;
    const f32x4* p = (const f32x4*)(ef + (e << 5) + (g << 3));
    f32x4 v0 = p[0], v1 = p[1];
    bf16x8 a;
    a[0] = (__bf16)v0[0]; a[1] = (__bf16)v0[1]; a[2] = (__bf16)v0[2]; a[3] = (__bf16)v0[3];
    a[4] = (__bf16)v1[0]; a[5] = (__bf16)v1[1]; a[6] = (__bf16)v1[2]; a[7] = (__bf16)v1[3];
    afr[as] = a;
  }

  __syncthreads();

  f32x4 acc[4];
#pragma unroll
  for (int i = 0; i < 4; ++i) { acc[i][0]=0.f; acc[i][1]=0.f; acc[i][2]=0.f; acc[i][3]=0.f; }

  const bf16x8* WpV = (const bf16x8*)Wp;

  // identical depth-2 prefetch structure to edge5
  bf16x8 bfrA = WpV[(0 * 4 + w) * 64 + l];
  float  bvA  = bp[(0 * 4 + w) * 16 + c];
  bf16x8 bfrB = WpV[(1 * 4 + w) * 64 + l];
  float  bvB  = bp[(1 * 4 + w) * 16 + c];

#pragma unroll 8
  for (int dl = 0; dl < 64; dl += 2) {
    {
      const bf16x8 bcur = bfrA;
      const float  bvc  = bvA;
      if (dl + 2 < 64) {
        bfrA = WpV[((dl + 2) * 4 + w) * 64 + l];
        bvA  = bp[((dl + 2) * 4 + w) * 16 + c];
      }
#pragma unroll
      for (int as = 0; as < 4; ++as) {
        const f32x4 hvf = *(const f32x4*)&hs[dl * EPF + as * 16 + (g << 2)];
        asm volatile("" :: "v"(hvf[0]), "v"(hvf[1]), "v"(hvf[2]), "v"(hvf[3]));  // keep ds_read
        acc[as] = __builtin_amdgcn_mfma_f32_16x16x32_bf16(afr[as], bcur, acc[as], 0, 0, 0);
      }
      asm volatile("" :: "v"(bvc));   // keep bias load
    }
    {
      const bf16x8 bcur = bfrB;
      const float  bvc  = bvB;
      if (dl + 3 < 64) {
        bfrB = WpV[((dl + 3) * 4 + w) * 64 + l];
        bvB  = bp[((dl + 3) * 4 + w) * 16 + c];
      }
#pragma unroll
      for (int as = 0; as < 4; ++as) {
        const f32x4 hvf = *(const f32x4*)&hs[(dl + 1) * EPF + as * 16 + (g << 2)];
        asm volatile("" :: "v"(hvf[0]), "v"(hvf[1]), "v"(hvf[2]), "v"(hvf[3]));
        acc[as] = __builtin_amdgcn_mfma_f32_16x16x32_bf16(afr[as], bcur, acc[as], 0, 0, 0);
      }
      asm volatile("" :: "v"(bvc));
    }
  }

  if (blockIdx.x < 1024) {
    const int hbase = (w << 4) + c;
#pragma unroll
    for (int as = 0; as < 4; ++as) {
      const int ebase = eblk + as * 16 + (g << 2);
      m[((ebase + 0) << 6) + hbase] = acc[as][0];
      m[((ebase + 1) << 6) + hbase] = acc[as][1];
      m[((ebase + 2) << 6) + hbase] = acc[as][2];
      m[((ebase + 3) << 6) + hbase] = acc[as][3];
    }
  }
}

// ---- edge compute (REAL, R7 proven 48us): m[e][h] = sum_d relu(...)*h_src; hist fused ----
__global__ __launch_bounds__(256, 2) void edge5_kernel(
    const float* __restrict__ nf, const float* __restrict__ ef,
    const int* __restrict__ src, const int* __restrict__ dst,
    const __bf16* __restrict__ Wp, const float* __restrict__ bp,
    float* __restrict__ m, int* __restrict__ cnt_i) {
  __shared__ float hs[64 * EPF];
  const int t = threadIdx.x;
  const int eblk = blockIdx.x << 6;

  {
    const int el = t & 63, q = t >> 6;
    const int srow = src[eblk + el];
    const f32x4* nfr = (const f32x4*)(nf + (srow << 6) + (q << 4));
#pragma unroll
    for (int i = 0; i < 4; ++i) {
      f32x4 v = nfr[i];
      const int dbase = (q << 4) + i * 4;
      hs[(dbase + 0) * EPF + el] = v[0];
      hs[(dbase + 1) * EPF + el] = v[1];
      hs[(dbase + 2) * EPF + el] = v[2];
      hs[(dbase + 3) * EPF + el] = v[3];
    }
  }

  if (t < 64) atomicAdd(&cnt_i[dst[eblk + t]], 1);

  const int w = t >> 6, l = t & 63;
  const int c = l & 15, g = l >> 4;

  bf16x8 afr[4];
#pragma unroll
  for (int as = 0; as < 4; ++as) {
    const int e = eblk + as * 16 + c;
    const f32x4* p = (const f32x4*)(ef + (e << 5) + (g << 3));
    f32x4 v0 = p[0], v1 = p[1];
    bf16x8 a;
    a[0] = (__bf16)v0[0]; a[1] = (__bf16)v0[1]; a[2] = (__bf16)v0[2]; a[3] = (__bf16)v0[3];
    a[4] = (__bf16)v1[0]; a[5] = (__bf16)v1[1]; a[6] = (__bf16)v1[2]; a[7] = (__bf16)v1[3];
    afr[as] = a;
  }

  __syncthreads();

  f32x2 accA[4], accB[4];
#pragma unroll
  for (int i = 0; i < 4; ++i) {
    accA[i][0] = 0.f; accA[i][1] = 0.f;
    accB[i][0] = 0.f; accB[i][1] = 0.f;
  }

  const bf16x8* WpV = (const bf16x8*)Wp;

  bf16x8 bfrA = WpV[(0 * 4 + w) * 64 + l];
  float  bvA  = bp[(0 * 4 + w) * 16 + c];
  bf16x8 bfrB = WpV[(1 * 4 + w) * 64 + l];
  float  bvB  = bp[(1 * 4 + w) * 16 + c];

#pragma unroll 8
  for (int dl = 0; dl < 64; dl += 2) {
    {
      const bf16x8 bcur = bfrA;
      const f32x4 cb = {bvA, bvA, bvA, bvA};
      if (dl + 2 < 64) {
        bfrA = WpV[((dl + 2) * 4 + w) * 64 + l];
        bvA  = bp[((dl + 2) * 4 + w) * 16 + c];
      }
#pragma unroll
      for (int as = 0; as < 4; ++as) {
        const f32x4 hvf = *(const f32x4*)&hs[dl * EPF + as * 16 + (g << 2)];
        f32x4 tmp = __builtin_amdgcn_mfma_f32_16x16x32_bf16(afr[as], bcur, cb, 0, 0, 0);
        f32x2 tl = {fmaxf(tmp[0], 0.f), fmaxf(tmp[1], 0.f)};
        f32x2 th = {fmaxf(tmp[2], 0.f), fmaxf(tmp[3], 0.f)};
        f32x2 hl = __builtin_shufflevector(hvf, hvf, 0, 1);
        f32x2 hh = __builtin_shufflevector(hvf, hvf, 2, 3);
        asm("v_pk_fma_f32 %0, %1, %2, %0" : "+v"(accA[as]) : "v"(tl), "v"(hl));
        asm("v_pk_fma_f32 %0, %1, %2, %0" : "+v"(accB[as]) : "v"(th), "v"(hh));
      }
    }
    {
      const bf16x8 bcur = bfrB;
      const f32x4 cb = {bvB, bvB, bvB, bvB};
      if (dl + 3 < 64) {
        bfrB = WpV[((dl + 3) * 4 + w) * 64 + l];
        bvB  = bp[((dl + 3) * 4 + w) * 16 + c];
      }
#pragma unroll
      for (int as = 0; as < 4; ++as) {
        const f32x4 hvf = *(const f32x4*)&hs[(dl + 1) * EPF + as * 16 + (g << 2)];
        f32x4 tmp = __builtin_amdgcn_mfma_f32_16x16x32_bf16(afr[as], bcur, cb, 0, 0, 0);
        f32x2 tl = {fmaxf(tmp[0], 0.f), fmaxf(tmp[1], 0.f)};
        f32x2 th = {fmaxf(tmp[2], 0.f), fmaxf(tmp[3], 0.f)};
        f32x2 hl = __builtin_shufflevector(hvf, hvf, 0, 1);
        f32x2 hh = __builtin_shufflevector(hvf, hvf, 2, 3);
        asm("v_pk_fma_f32 %0, %1, %2, %0" : "+v"(accA[as]) : "v"(tl), "v"(hl));
        asm("v_pk_fma_f32 %0, %1, %2, %0" : "+v"(accB[as]) : "v"(th), "v"(hh));
      }
    }
  }

  const int hbase = (w << 4) + c;
#pragma unroll
  for (int as = 0; as < 4; ++as) {
    const int ebase = eblk + as * 16 + (g << 2);
    m[((ebase + 0) << 6) + hbase] = accA[as][0];
    m[((ebase + 1) << 6) + hbase] = accA[as][1];
    m[((ebase + 2) << 6) + hbase] = accB[as][0];
    m[((ebase + 3) << 6) + hbase] = accB[as][1];
  }
}

// ---- final: gather-mean per dst (CSR) fused with out = relu(concat@Wn + bn) ----
__global__ __launch_bounds__(256) void final5_kernel(
    const float* __restrict__ nf, const float* __restrict__ m,
    const int* __restrict__ off, const int* __restrict__ eid,
    const float* __restrict__ Wn, const float* __restrict__ bn,
    float* __restrict__ out) {
  __shared__ float wn_s[128 * 64];   // 32 KB
  __shared__ float hn_s[8 * 64];     // 2 KB
  const int t = threadIdx.x;
#pragma unroll
  for (int i = 0; i < 8; ++i)
    ((f32x4*)wn_s)[i * 256 + t] = ((const f32x4*)Wn)[i * 256 + t];

  const int w = t >> 6, h = t & 63;
  const int row0 = blockIdx.x * 8 + w * 2;

#pragma unroll
  for (int i = 0; i < 2; ++i) {
    const int d = row0 + i;
    const int lo = off[d], hi = off[d + 1];
    float a0 = 0.f, a1 = 0.f;
    int j = lo;
    for (; j + 2 <= hi; j += 2) {
      const int e0 = eid[j], e1 = eid[j + 1];
      a0 += m[(e0 << 6) + h];
      a1 += m[(e1 << 6) + h];
    }
    if (j < hi) a0 += m[(eid[j] << 6) + h];
    const float a = a0 + a1;
    hn_s[(w * 2 + i) * 64 + h] = (hi > lo) ? a * (1.f / (float)(hi - lo)) : 0.f;
  }
  __syncthreads();

  const float bv = bn[h];
  float acc[2] = {bv, bv};
#pragma unroll 4
  for (int k = 0; k < 64; ++k) {
    const float wv = wn_s[k * 64 + h];
#pragma unroll
    for (int i = 0; i < 2; ++i)
      acc[i] = fmaf(nf[(row0 + i) * 64 + k], wv, acc[i]);
  }
#pragma unroll 4
  for (int k = 0; k < 64; ++k) {
    const float wv = wn_s[(64 + k) * 64 + h];
#pragma unroll
    for (int i = 0; i < 2; ++i)
      acc[i] = fmaf(hn_s[(w * 2 + i) * 64 + k], wv, acc[i]);
  }
#pragma unroll
  for (int i = 0; i < 2; ++i)
    out[(row0 + i) * 64 + h] = fmaxf(acc[i], 0.f);
}

// ================= atomic fallback (R3, proven) =================

__global__ __launch_bounds__(256, 4) void edge_kernel(
    const float* __restrict__ nf, const float* __restrict__ ef,
    const int* __restrict__ src, const int* __restrict__ dst,
    const __bf16* __restrict__ Wp, const float* __restrict__ bp,
    float* __restrict__ msum, float* __restrict__ cnt_g) {
  __shared__ __bf16 hs[64 * EPW];
  const int t = threadIdx.x;
  const int eblk = blockIdx.x << 6;
  {
    const int el = t & 63, q = t >> 6;
    const int srow = src[eblk + el];
    const f32x4* nfr = (const f32x4*)(nf + (srow << 6) + (q << 4));
#pragma unroll
    for (int i = 0; i < 4; ++i) {
      f32x4 v = nfr[i];
      const int dbase = (q << 4) + i * 4;
      hs[(dbase + 0) * EPW + el] = (__bf16)v[0];
      hs[(dbase + 1) * EPW + el] = (__bf16)v[1];
      hs[(dbase + 2) * EPW + el] = (__bf16)v[2];
      hs[(dbase + 3) * EPW + el] = (__bf16)v[3];
    }
  }
  const int w = t >> 6, l = t & 63, c = l & 15, g = l >> 4;
  bf16x8 afr[4];
#pragma unroll
  for (int as = 0; as < 4; ++as) {
    const int e = eblk + as * 16 + c;
    const f32x4* p = (const f32x4*)(ef + (e << 5) + (g << 3));
    f32x4 v0 = p[0], v1 = p[1];
    bf16x8 a;
    a[0] = (__bf16)v0[0]; a[1] = (__bf16)v0[1]; a[2] = (__bf16)v0[2]; a[3] = (__bf16)v0[3];
    a[4] = (__bf16)v1[0]; a[5] = (__bf16)v1[1]; a[6] = (__bf16)v1[2]; a[7] = (__bf16)v1[3];
    afr[as] = a;
  }
  __syncthreads();
  f32x4 acc[4];
#pragma unroll
  for (int i = 0; i < 4; ++i) { acc[i][0]=0.f; acc[i][1]=0.f; acc[i][2]=0.f; acc[i][3]=0.f; }
  const bf16x8* WpV = (const bf16x8*)Wp;
  const f32x4 zero = {0.f, 0.f, 0.f, 0.f};
#pragma unroll 4
  for (int d0 = 0; d0 < 64; ++d0) {
    const int T = d0 * 4 + w;
    const bf16x8 bfr = WpV[T * 64 + l];
    const float bv = bp[T * 16 + c];
    const f32x4 cb = {bv, bv, bv, bv};
#pragma unroll
    for (int as = 0; as < 4; ++as) {
      const bf16x4 hv = *(const bf16x4*)&hs[d0 * EPW + as * 16 + (g << 2)];
      const f32x4 hvf = {(float)hv[0], (float)hv[1], (float)hv[2], (float)hv[3]};
      f32x4 tmp = __builtin_amdgcn_mfma_f32_16x16x32_bf16(afr[as], bfr, cb, 0, 0, 0);
      tmp = __builtin_elementwise_max(tmp, zero);
      acc[as] = tmp * hvf + acc[as];
    }
  }
#pragma unroll
  for (int as = 0; as < 4; ++as)
#pragma unroll
    for (int r = 0; r < 4; ++r) {
      const int e = eblk + as * 16 + (g << 2) + r;
      const int dd = dst[e];
      unsafeAtomicAdd(msum + (dd << 6) + (w << 4) + c, acc[as][r]);
      if (w == 0 && c == 0) unsafeAtomicAdd(cnt_g + dd, 1.0f);
    }
}

__global__ __launch_bounds__(256) void final_kernel(
    const float* __restrict__ nf, const float* __restrict__ msum,
    const float* __restrict__ cnt, const float* __restrict__ Wn,
    const float* __restrict__ bn, float* __restrict__ out) {
  __shared__ float wn_s[128 * 64];
  const int t = threadIdx.x;
#pragma unroll
  for (int i = 0; i < 8; ++i)
    ((f32x4*)wn_s)[i * 256 + t] = ((const f32x4*)Wn)[i * 256 + t];
  __syncthreads();
  const int w = t >> 6, h = t & 63;
  const int row0 = blockIdx.x * 16 + w * 4;
  const float bv = bn[h];
  float acc[4] = {bv, bv, bv, bv};
  float s[4];
#pragma unroll
  for (int i = 0; i < 4; ++i) {
    const float cv = cnt[row0 + i];
    s[i] = cv > 0.f ? 1.f / cv : 0.f;
  }
#pragma unroll 4
  for (int k = 0; k < 64; ++k) {
    const float wv = wn_s[k * 64 + h];
#pragma unroll
    for (int i = 0; i < 4; ++i) acc[i] = fmaf(nf[(row0 + i) * 64 + k], wv, acc[i]);
  }
#pragma unroll 4
  for (int k = 0; k < 64; ++k) {
    const float wv = wn_s[(64 + k) * 64 + h];
#pragma unroll
    for (int i = 0; i < 4; ++i) acc[i] = fmaf(msum[(row0 + i) * 64 + k] * s[i], wv, acc[i]);
  }
#pragma unroll
  for (int i = 0; i < 4; ++i) out[(row0 + i) * 64 + h] = fmaxf(acc[i], 0.f);
}

// ================= launcher =================

extern "C" void kernel_launch(void* const* d_in, const int* in_sizes, int n_in,
                              void* d_out, int out_size, void* d_ws, size_t ws_size,
                              hipStream_t stream) {
  const float* nf  = (const float*)d_in[0];
  const float* ef  = (const float*)d_in[1];
  const int*   src = (const int*)d_in[2];
  const int*   dst = (const int*)d_in[3];
  const float* We  = (const float*)d_in[4];
  const float* be  = (const float*)d_in[5];
  const float* Wn  = (const float*)d_in[6];
  const float* bn  = (const float*)d_in[7];
  float* out = (float*)d_out;
  char* ws = (char*)d_ws;

  const size_t MB = 16777216;  // m buffer bytes (E*64*4)
  const size_t T_OFF    = MB;
  const size_t T_CURSOR = T_OFF + 36864;
  const size_t T_CNTI   = T_CURSOR + 32768;
  const size_t T_EID    = T_CNTI + 32768;
  const size_t T_WP     = T_EID + 262144;
  const size_t T_BP     = T_WP + 262144;
  const size_t NEED     = T_BP + 16384;      // ~17.4 MB

  if (ws_size >= NEED) {
    float*  m      = (float*)ws;
    int*    off    = (int*)(ws + T_OFF);
    int*    cursor = (int*)(ws + T_CURSOR);
    int*    cnt_i  = (int*)(ws + T_CNTI);
    int*    eid    = (int*)(ws + T_EID);
    __bf16* Wp     = (__bf16*)(ws + T_WP);
    float*  bp     = (float*)(ws + T_BP);

    hipMemsetAsync(cnt_i, 0, 32768, stream);
    prep_kernel<<<64, 256, 0, stream>>>(We, be, Wp, bp);
    // ABLATION dispatch (x4 grid; writes m garbage, fully overwritten by edge5 below)
    edge_ablate_kernel<<<4096, 256, 0, stream>>>(nf, ef, src, Wp, bp, m);
    edge5_kernel<<<E_TOT / 64, 256, 0, stream>>>(nf, ef, src, dst, Wp, bp, m, cnt_i);
    scan_kernel<<<1, 256, 0, stream>>>(cnt_i, off, cursor);
    fill_kernel<<<E_TOT / 256, 256, 0, stream>>>(dst, cursor, eid);
    final5_kernel<<<NDST / 8, 256, 0, stream>>>(nf, m, off, eid, Wn, bn, out);
  } else {
    // atomic fallback
    float* msum = (float*)ws;
    float* cnt  = (float*)(ws + 2097152);
    const size_t need = 2097152 + 32768 + 262144 + 16384;
    __bf16* Wp;
    float*  bp;
    if (ws_size >= need) {
      Wp = (__bf16*)(ws + 2097152 + 32768);
      bp = (float*)(ws + 2097152 + 32768 + 262144);
    } else {
      Wp = (__bf16*)d_out;
      bp = (float*)((char*)d_out + 262144);
    }
    hipMemsetAsync(msum, 0, 2097152 + 32768, stream);
    prep_kernel<<<64, 256, 0, stream>>>(We, be, Wp, bp);
    edge_kernel<<<E_TOT / 64, 256, 0, stream>>>(nf, ef, src, dst, Wp, bp, msum, cnt);
    final_kernel<<<NDST / 16, 256, 0, stream>>>(nf, msum, cnt, Wn, bn, out);
  }
}

// Round 12
// 78.385 us; speedup vs baseline: 1.9457x; 1.9457x over previous
//
#include <hip/hip_runtime.h>

// ECConv: out = relu(concat(nf[:8192], mean_seg(relu(EF@We+be).reshape(E,64,64) @ h_src)) @ Wn + bn)
// Sizes: E=65536, N_SRC=32768, N_DST=8192, EDGE_IN=32, NODE_IN=64, HIDDEN=64
// R12: pipelined epilogue. R11 ablation: edge5 minus epilogue = 21.3us/unit (MFMA-busy ~= 
//      theoretical), with epilogue = 48us -> +26.7us is MFMA->VALU RAW hazard (tmp consumed
//      immediately after mfma). Fix: 2-set (E/O) software pipeline — consume section d0-2's
//      tmps while issuing d0's MFMAs; hvf prefetched one section ahead. +~64 VGPR (ok at
//      launch_bounds(256,2) -> 256 cap; spill tell = WRITE >> 18.4MB).
// Lessons: R2 fp32 atomics memory-side. R4 serial scan 20us. R5/R9 reg-pressure spills
//      (WRITE>>payload). R6 sequential dispatches don't stack. R10 zero-global-load loop
//      = 54us -> loads were never the binder. R11 ablation: epilogue hazard owns 27/48us.

typedef float f32x4 __attribute__((ext_vector_type(4)));
typedef float f32x2 __attribute__((ext_vector_type(2)));
typedef __bf16 bf16x8 __attribute__((ext_vector_type(8)));
typedef __bf16 bf16x4 __attribute__((ext_vector_type(4)));

#define E_TOT   65536
#define NDST    8192
#define EPW     72    // bf16 hs pad (atomic-fallback kernel)
#define EPF     68    // f32 hs pad (fast kernel)

// ---- prep: pack We (fp32 [32][4096]) -> MFMA-B fragment order bf16 + bias tiles ----
// Tile T = d0*4 + ht covers GEMM cols n = (ht*16 + c)*64 + d0, c=0..15.
// B frag for mfma_f32_16x16x32_bf16: lane l holds B[k=(l>>4)*8+j][col=l&15], j=0..7.
__global__ __launch_bounds__(256) void prep_kernel(
    const float* __restrict__ We, const float* __restrict__ be,
    __bf16* __restrict__ Wp, float* __restrict__ bp) {
  int tid = blockIdx.x * 256 + threadIdx.x;       // 16384 packers
  int T = tid >> 6, l = tid & 63;
  int d0 = T >> 2, ht = T & 3;
  int c = l & 15, kg = l >> 4;
  int ncol = (ht * 16 + c) * 64 + d0;
  bf16x8 v;
#pragma unroll
  for (int j = 0; j < 8; ++j) v[j] = (__bf16)We[(kg * 8 + j) * 4096 + ncol];
  *reinterpret_cast<bf16x8*>(Wp + tid * 8) = v;
  if (l < 16) bp[T * 16 + l] = be[(ht * 16 + l) * 64 + d0];
}

// ---- parallel exclusive scan over 8192 bins (one block, shfl + LDS) ----
__global__ __launch_bounds__(256) void scan_kernel(const int* __restrict__ cnt_i,
                                                   int* __restrict__ off,
                                                   int* __restrict__ cursor) {
  __shared__ int wsum[4];
  const int t = threadIdx.x;
  const int lane = t & 63, w = t >> 6;
  int vals[32];
  const int4* cp = (const int4*)(cnt_i + t * 32);
#pragma unroll
  for (int i = 0; i < 8; ++i) {
    int4 v = cp[i];
    vals[i * 4 + 0] = v.x; vals[i * 4 + 1] = v.y;
    vals[i * 4 + 2] = v.z; vals[i * 4 + 3] = v.w;
  }
  int loc[32];
  int s = 0;
#pragma unroll
  for (int i = 0; i < 32; ++i) { loc[i] = s; s += vals[i]; }
  int inc = s;
#pragma unroll
  for (int d = 1; d < 64; d <<= 1) {
    int n = __shfl_up(inc, d, 64);
    if (lane >= d) inc += n;
  }
  if (lane == 63) wsum[w] = inc;
  __syncthreads();
  int base = inc - s;
#pragma unroll
  for (int i = 0; i < 4; ++i)
    if (i < w) base += wsum[i];
#pragma unroll
  for (int i = 0; i < 32; ++i) {
    int v = base + loc[i];
    off[t * 32 + i] = v;
    cursor[t * 32 + i] = v;
  }
  if (t == 255) off[8192] = E_TOT;
}

// ---- fill: scatter edge ids into CSR order (int atomics on cursor) ----
__global__ void fill_kernel(const int* __restrict__ dst, int* __restrict__ cursor,
                            int* __restrict__ eid) {
  int e = blockIdx.x * 256 + threadIdx.x;
  int slot = atomicAdd(&cursor[dst[e]], 1);
  eid[slot] = e;
}

// ---- edge compute (pipelined epilogue): m[e][h] = sum_d relu(ef@We+be)*h_src ----
// 4 waves, 64 edges; wave w owns h-quadrant ht=w; grid 1024; hist fused.
// Pipeline: consume tmp-set of section d0-2 (VALU) while issuing section d0's MFMAs.
__global__ __launch_bounds__(256, 2) void edge9_kernel(
    const float* __restrict__ nf, const float* __restrict__ ef,
    const int* __restrict__ src, const int* __restrict__ dst,
    const __bf16* __restrict__ Wp, const float* __restrict__ bp,
    float* __restrict__ m, int* __restrict__ cnt_i) {
  __shared__ float hs[64 * EPF];   // transposed f32 h_src: hs[d][e_local], 17.4 KB
  const int t = threadIdx.x;
  const int eblk = blockIdx.x << 6;

  // stage h_src transposed: thread t -> edge el=t&63, d-quarter q=t>>6 (16 d each)
  {
    const int el = t & 63, q = t >> 6;
    const int srow = src[eblk + el];
    const f32x4* nfr = (const f32x4*)(nf + (srow << 6) + (q << 4));
#pragma unroll
    for (int i = 0; i < 4; ++i) {
      f32x4 v = nfr[i];
      const int dbase = (q << 4) + i * 4;
      hs[(dbase + 0) * EPF + el] = v[0];
      hs[(dbase + 1) * EPF + el] = v[1];
      hs[(dbase + 2) * EPF + el] = v[2];
      hs[(dbase + 3) * EPF + el] = v[3];
    }
  }

  // fused dst histogram (cnt_i zeroed by memset)
  if (t < 64) atomicAdd(&cnt_i[dst[eblk + t]], 1);

  const int w = t >> 6, l = t & 63;
  const int c = l & 15, g = l >> 4;

  // A fragments: lane holds A[row=c][k=g*8+j] for 4 edge-groups of 16
  bf16x8 afr[4];
#pragma unroll
  for (int as = 0; as < 4; ++as) {
    const int e = eblk + as * 16 + c;
    const f32x4* p = (const f32x4*)(ef + (e << 5) + (g << 3));
    f32x4 v0 = p[0], v1 = p[1];
    bf16x8 a;
    a[0] = (__bf16)v0[0]; a[1] = (__bf16)v0[1]; a[2] = (__bf16)v0[2]; a[3] = (__bf16)v0[3];
    a[4] = (__bf16)v1[0]; a[5] = (__bf16)v1[1]; a[6] = (__bf16)v1[2]; a[7] = (__bf16)v1[3];
    afr[as] = a;
  }

  f32x2 accA[4], accB[4];   // [as]; rows (g*4+0,g*4+1) / (g*4+2,g*4+3)
#pragma unroll
  for (int i = 0; i < 4; ++i) {
    accA[i][0] = 0.f; accA[i][1] = 0.f;
    accB[i][0] = 0.f; accB[i][1] = 0.f;
  }

  const bf16x8* WpV = (const bf16x8*)Wp;

  // B/bias depth-2 prefetch regs
  bf16x8 bfrA = WpV[(0 * 4 + w) * 64 + l];
  float  bvA  = bp[(0 * 4 + w) * 16 + c];
  bf16x8 bfrB = WpV[(1 * 4 + w) * 64 + l];
  float  bvB  = bp[(1 * 4 + w) * 16 + c];

  __syncthreads();   // hs ready

  const int hoff = g << 2;   // + as*16 per fragment

  // pipeline register sets
  f32x4 tE0, tE1, tE2, tE3, tO0, tO1, tO2, tO3;   // MFMA results (even/odd sections)
  f32x4 hE0, hE1, hE2, hE3, hO0, hO1, hO2, hO3;   // matching h_src vectors

#define ISSUE_SET(T0, T1, T2, T3, BFR, BV)                                         \
  {                                                                                \
    const f32x4 cb = {BV, BV, BV, BV};                                             \
    T0 = __builtin_amdgcn_mfma_f32_16x16x32_bf16(afr[0], BFR, cb, 0, 0, 0);        \
    T1 = __builtin_amdgcn_mfma_f32_16x16x32_bf16(afr[1], BFR, cb, 0, 0, 0);        \
    T2 = __builtin_amdgcn_mfma_f32_16x16x32_bf16(afr[2], BFR, cb, 0, 0, 0);        \
    T3 = __builtin_amdgcn_mfma_f32_16x16x32_bf16(afr[3], BFR, cb, 0, 0, 0);        \
  }

#define LOADHV_SET(H0, H1, H2, H3, D0)                                             \
  {                                                                                \
    H0 = *(const f32x4*)&hs[(D0) * EPF +  0 + hoff];                               \
    H1 = *(const f32x4*)&hs[(D0) * EPF + 16 + hoff];                               \
    H2 = *(const f32x4*)&hs[(D0) * EPF + 32 + hoff];                               \
    H3 = *(const f32x4*)&hs[(D0) * EPF + 48 + hoff];                               \
  }

#define CONSUME_ONE(AS, TT, HH)                                                    \
  {                                                                                \
    f32x2 p, hl, hh;                                                               \
    hl = __builtin_shufflevector(HH, HH, 0, 1);                                    \
    hh = __builtin_shufflevector(HH, HH, 2, 3);                                    \
    p[0] = fmaxf(TT[0], 0.f); p[1] = fmaxf(TT[1], 0.f);                            \
    asm("v_pk_fma_f32 %0, %1, %2, %0" : "+v"(accA[AS]) : "v"(p), "v"(hl));         \
    p[0] = fmaxf(TT[2], 0.f); p[1] = fmaxf(TT[3], 0.f);                            \
    asm("v_pk_fma_f32 %0, %1, %2, %0" : "+v"(accB[AS]) : "v"(p), "v"(hh));         \
  }

#define CONSUME_SET(T0, T1, T2, T3, H0, H1, H2, H3)                                \
  CONSUME_ONE(0, T0, H0) CONSUME_ONE(1, T1, H1)                                    \
  CONSUME_ONE(2, T2, H2) CONSUME_ONE(3, T3, H3)

  // prologue: issue sections d0=0 (E) and d0=1 (O); no consumption yet
  ISSUE_SET(tE0, tE1, tE2, tE3, bfrA, bvA)
  LOADHV_SET(hE0, hE1, hE2, hE3, 0)
  bfrA = WpV[(2 * 4 + w) * 64 + l];
  bvA  = bp[(2 * 4 + w) * 16 + c];
  ISSUE_SET(tO0, tO1, tO2, tO3, bfrB, bvB)
  LOADHV_SET(hO0, hO1, hO2, hO3, 1)
  bfrB = WpV[(3 * 4 + w) * 64 + l];
  bvB  = bp[(3 * 4 + w) * 16 + c];

#pragma unroll 4
  for (int d0 = 2; d0 < 64; d0 += 2) {
    // consume E (d0-2), reissue E (d0)
    CONSUME_SET(tE0, tE1, tE2, tE3, hE0, hE1, hE2, hE3)
    ISSUE_SET(tE0, tE1, tE2, tE3, bfrA, bvA)
    LOADHV_SET(hE0, hE1, hE2, hE3, d0)
    if (d0 + 2 < 64) {
      bfrA = WpV[((d0 + 2) * 4 + w) * 64 + l];
      bvA  = bp[((d0 + 2) * 4 + w) * 16 + c];
    }
    // consume O (d0-1), reissue O (d0+1)
    CONSUME_SET(tO0, tO1, tO2, tO3, hO0, hO1, hO2, hO3)
    ISSUE_SET(tO0, tO1, tO2, tO3, bfrB, bvB)
    LOADHV_SET(hO0, hO1, hO2, hO3, d0 + 1)
    if (d0 + 3 < 64) {
      bfrB = WpV[((d0 + 3) * 4 + w) * 64 + l];
      bvB  = bp[((d0 + 3) * 4 + w) * 16 + c];
    }
  }

  // epilogue: consume last two sections (d0=62 E, d0=63 O)
  CONSUME_SET(tE0, tE1, tE2, tE3, hE0, hE1, hE2, hE3)
  CONSUME_SET(tO0, tO1, tO2, tO3, hO0, hO1, hO2, hO3)

#undef ISSUE_SET
#undef LOADHV_SET
#undef CONSUME_ONE
#undef CONSUME_SET

  // stores: per (as,row): 16 lanes x 4B = 64B segments
  const int hbase = (w << 4) + c;
#pragma unroll
  for (int as = 0; as < 4; ++as) {
    const int ebase = eblk + as * 16 + (g << 2);
    m[((ebase + 0) << 6) + hbase] = accA[as][0];
    m[((ebase + 1) << 6) + hbase] = accA[as][1];
    m[((ebase + 2) << 6) + hbase] = accB[as][0];
    m[((ebase + 3) << 6) + hbase] = accB[as][1];
  }
}

// ---- final: gather-mean per dst (CSR) fused with out = relu(concat@Wn + bn) ----
__global__ __launch_bounds__(256) void final5_kernel(
    const float* __restrict__ nf, const float* __restrict__ m,
    const int* __restrict__ off, const int* __restrict__ eid,
    const float* __restrict__ Wn, const float* __restrict__ bn,
    float* __restrict__ out) {
  __shared__ float wn_s[128 * 64];   // 32 KB
  __shared__ float hn_s[8 * 64];     // 2 KB
  const int t = threadIdx.x;
#pragma unroll
  for (int i = 0; i < 8; ++i)
    ((f32x4*)wn_s)[i * 256 + t] = ((const f32x4*)Wn)[i * 256 + t];

  const int w = t >> 6, h = t & 63;
  const int row0 = blockIdx.x * 8 + w * 2;

#pragma unroll
  for (int i = 0; i < 2; ++i) {
    const int d = row0 + i;
    const int lo = off[d], hi = off[d + 1];
    float a0 = 0.f, a1 = 0.f;
    int j = lo;
    for (; j + 2 <= hi; j += 2) {
      const int e0 = eid[j], e1 = eid[j + 1];
      a0 += m[(e0 << 6) + h];
      a1 += m[(e1 << 6) + h];
    }
    if (j < hi) a0 += m[(eid[j] << 6) + h];
    const float a = a0 + a1;
    hn_s[(w * 2 + i) * 64 + h] = (hi > lo) ? a * (1.f / (float)(hi - lo)) : 0.f;
  }
  __syncthreads();

  const float bv = bn[h];
  float acc[2] = {bv, bv};
#pragma unroll 4
  for (int k = 0; k < 64; ++k) {
    const float wv = wn_s[k * 64 + h];
#pragma unroll
    for (int i = 0; i < 2; ++i)
      acc[i] = fmaf(nf[(row0 + i) * 64 + k], wv, acc[i]);
  }
#pragma unroll 4
  for (int k = 0; k < 64; ++k) {
    const float wv = wn_s[(64 + k) * 64 + h];
#pragma unroll
    for (int i = 0; i < 2; ++i)
      acc[i] = fmaf(hn_s[(w * 2 + i) * 64 + k], wv, acc[i]);
  }
#pragma unroll
  for (int i = 0; i < 2; ++i)
    out[(row0 + i) * 64 + h] = fmaxf(acc[i], 0.f);
}

// ================= atomic fallback (R3, proven) =================

__global__ __launch_bounds__(256, 4) void edge_kernel(
    const float* __restrict__ nf, const float* __restrict__ ef,
    const int* __restrict__ src, const int* __restrict__ dst,
    const __bf16* __restrict__ Wp, const float* __restrict__ bp,
    float* __restrict__ msum, float* __restrict__ cnt_g) {
  __shared__ __bf16 hs[64 * EPW];
  const int t = threadIdx.x;
  const int eblk = blockIdx.x << 6;
  {
    const int el = t & 63, q = t >> 6;
    const int srow = src[eblk + el];
    const f32x4* nfr = (const f32x4*)(nf + (srow << 6) + (q << 4));
#pragma unroll
    for (int i = 0; i < 4; ++i) {
      f32x4 v = nfr[i];
      const int dbase = (q << 4) + i * 4;
      hs[(dbase + 0) * EPW + el] = (__bf16)v[0];
      hs[(dbase + 1) * EPW + el] = (__bf16)v[1];
      hs[(dbase + 2) * EPW + el] = (__bf16)v[2];
      hs[(dbase + 3) * EPW + el] = (__bf16)v[3];
    }
  }
  const int w = t >> 6, l = t & 63, c = l & 15, g = l >> 4;
  bf16x8 afr[4];
#pragma unroll
  for (int as = 0; as < 4; ++as) {
    const int e = eblk + as * 16 + c;
    const f32x4* p = (const f32x4*)(ef + (e << 5) + (g << 3));
    f32x4 v0 = p[0], v1 = p[1];
    bf16x8 a;
    a[0] = (__bf16)v0[0]; a[1] = (__bf16)v0[1]; a[2] = (__bf16)v0[2]; a[3] = (__bf16)v0[3];
    a[4] = (__bf16)v1[0]; a[5] = (__bf16)v1[1]; a[6] = (__bf16)v1[2]; a[7] = (__bf16)v1[3];
    afr[as] = a;
  }
  __syncthreads();
  f32x4 acc[4];
#pragma unroll
  for (int i = 0; i < 4; ++i) { acc[i][0]=0.f; acc[i][1]=0.f; acc[i][2]=0.f; acc[i][3]=0.f; }
  const bf16x8* WpV = (const bf16x8*)Wp;
  const f32x4 zero = {0.f, 0.f, 0.f, 0.f};
#pragma unroll 4
  for (int d0 = 0; d0 < 64; ++d0) {
    const int T = d0 * 4 + w;
    const bf16x8 bfr = WpV[T * 64 + l];
    const float bv = bp[T * 16 + c];
    const f32x4 cb = {bv, bv, bv, bv};
#pragma unroll
    for (int as = 0; as < 4; ++as) {
      const bf16x4 hv = *(const bf16x4*)&hs[d0 * EPW + as * 16 + (g << 2)];
      const f32x4 hvf = {(float)hv[0], (float)hv[1], (float)hv[2], (float)hv[3]};
      f32x4 tmp = __builtin_amdgcn_mfma_f32_16x16x32_bf16(afr[as], bfr, cb, 0, 0, 0);
      tmp = __builtin_elementwise_max(tmp, zero);
      acc[as] = tmp * hvf + acc[as];
    }
  }
#pragma unroll
  for (int as = 0; as < 4; ++as)
#pragma unroll
    for (int r = 0; r < 4; ++r) {
      const int e = eblk + as * 16 + (g << 2) + r;
      const int dd = dst[e];
      unsafeAtomicAdd(msum + (dd << 6) + (w << 4) + c, acc[as][r]);
      if (w == 0 && c == 0) unsafeAtomicAdd(cnt_g + dd, 1.0f);
    }
}

__global__ __launch_bounds__(256) void final_kernel(
    const float* __restrict__ nf, const float* __restrict__ msum,
    const float* __restrict__ cnt, const float* __restrict__ Wn,
    const float* __restrict__ bn, float* __restrict__ out) {
  __shared__ float wn_s[128 * 64];
  const int t = threadIdx.x;
#pragma unroll
  for (int i = 0; i < 8; ++i)
    ((f32x4*)wn_s)[i * 256 + t] = ((const f32x4*)Wn)[i * 256 + t];
  __syncthreads();
  const int w = t >> 6, h = t & 63;
  const int row0 = blockIdx.x * 16 + w * 4;
  const float bv = bn[h];
  float acc[4] = {bv, bv, bv, bv};
  float s[4];
#pragma unroll
  for (int i = 0; i < 4; ++i) {
    const float cv = cnt[row0 + i];
    s[i] = cv > 0.f ? 1.f / cv : 0.f;
  }
#pragma unroll 4
  for (int k = 0; k < 64; ++k) {
    const float wv = wn_s[k * 64 + h];
#pragma unroll
    for (int i = 0; i < 4; ++i) acc[i] = fmaf(nf[(row0 + i) * 64 + k], wv, acc[i]);
  }
#pragma unroll 4
  for (int k = 0; k < 64; ++k) {
    const float wv = wn_s[(64 + k) * 64 + h];
#pragma unroll
    for (int i = 0; i < 4; ++i) acc[i] = fmaf(msum[(row0 + i) * 64 + k] * s[i], wv, acc[i]);
  }
#pragma unroll
  for (int i = 0; i < 4; ++i) out[(row0 + i) * 64 + h] = fmaxf(acc[i], 0.f);
}

// ================= launcher =================

extern "C" void kernel_launch(void* const* d_in, const int* in_sizes, int n_in,
                              void* d_out, int out_size, void* d_ws, size_t ws_size,
                              hipStream_t stream) {
  const float* nf  = (const float*)d_in[0];
  const float* ef  = (const float*)d_in[1];
  const int*   src = (const int*)d_in[2];
  const int*   dst = (const int*)d_in[3];
  const float* We  = (const float*)d_in[4];
  const float* be  = (const float*)d_in[5];
  const float* Wn  = (const float*)d_in[6];
  const float* bn  = (const float*)d_in[7];
  float* out = (float*)d_out;
  char* ws = (char*)d_ws;

  const size_t MB = 16777216;  // m buffer bytes (E*64*4)
  const size_t T_OFF    = MB;
  const size_t T_CURSOR = T_OFF + 36864;
  const size_t T_CNTI   = T_CURSOR + 32768;
  const size_t T_EID    = T_CNTI + 32768;
  const size_t T_WP     = T_EID + 262144;
  const size_t T_BP     = T_WP + 262144;
  const size_t NEED     = T_BP + 16384;      // ~17.4 MB

  if (ws_size >= NEED) {
    float*  m      = (float*)ws;
    int*    off    = (int*)(ws + T_OFF);
    int*    cursor = (int*)(ws + T_CURSOR);
    int*    cnt_i  = (int*)(ws + T_CNTI);
    int*    eid    = (int*)(ws + T_EID);
    __bf16* Wp     = (__bf16*)(ws + T_WP);
    float*  bp     = (float*)(ws + T_BP);

    hipMemsetAsync(cnt_i, 0, 32768, stream);
    prep_kernel<<<64, 256, 0, stream>>>(We, be, Wp, bp);
    edge9_kernel<<<E_TOT / 64, 256, 0, stream>>>(nf, ef, src, dst, Wp, bp, m, cnt_i);
    scan_kernel<<<1, 256, 0, stream>>>(cnt_i, off, cursor);
    fill_kernel<<<E_TOT / 256, 256, 0, stream>>>(dst, cursor, eid);
    final5_kernel<<<NDST / 8, 256, 0, stream>>>(nf, m, off, eid, Wn, bn, out);
  } else {
    // atomic fallback
    float* msum = (float*)ws;
    float* cnt  = (float*)(ws + 2097152);
    const size_t need = 2097152 + 32768 + 262144 + 16384;
    __bf16* Wp;
    float*  bp;
    if (ws_size >= need) {
      Wp = (__bf16*)(ws + 2097152 + 32768);
      bp = (float*)(ws + 2097152 + 32768 + 262144);
    } else {
      Wp = (__bf16*)d_out;
      bp = (float*)((char*)d_out + 262144);
    }
    hipMemsetAsync(msum, 0, 2097152 + 32768, stream);
    prep_kernel<<<64, 256, 0, stream>>>(We, be, Wp, bp);
    edge_kernel<<<E_TOT / 64, 256, 0, stream>>>(nf, ef, src, dst, Wp, bp, msum, cnt);
    final_kernel<<<NDST / 16, 256, 0, stream>>>(nf, msum, cnt, Wn, bn, out);
  }
}

// Round 14
// 74.769 us; speedup vs baseline: 2.0398x; 1.0484x over previous
//
#include <hip/hip_runtime.h>

// ECConv: out = relu(concat(nf[:8192], mean_seg(relu(EF@We+be).reshape(E,64,64) @ h_src)) @ Wn + bn)
// Sizes: E=65536, N_SRC=32768, N_DST=8192, EDGE_IN=32, NODE_IN=64, HIDDEN=64
// R14: REVERT to R12's proven deterministic pipeline (edge9, 46.9us) after R13's operand-swap
//      kernel failed the determinism tripwire with an unexplained absmax shift (0.031->0.078
//      despite bit-identical derivation — unlocated race/codegen issue; parked until it can
//      be A/B'd with an explanation). Trim: cnt_i zeroing folded into prep (-1 dispatch).
// Lessons: R2 fp32 atomics memory-side. R4 serial scan 20us. R5/R9 reg-pressure spills
//      (WRITE>>payload tell). R6 sequential dispatches don't stack. R10 zero-global-load
//      loop = 54us -> loads never the binder. R11 ablation: 21.3us base + ~27us MFMA->VALU
//      hazard. R12 compiler collapses source SWP (VGPR 36) yet 46.9us. R13: unexplained
//      nondeterminism = do not ship; revert to proven.

typedef float f32x4 __attribute__((ext_vector_type(4)));
typedef float f32x2 __attribute__((ext_vector_type(2)));
typedef __bf16 bf16x8 __attribute__((ext_vector_type(8)));
typedef __bf16 bf16x4 __attribute__((ext_vector_type(4)));

#define E_TOT   65536
#define NDST    8192
#define EPW     72    // bf16 hs pad (atomic-fallback kernel)
#define EPF     68    // f32 hs pad (fast kernel)

// ---- prep: pack We (fp32 [32][4096]) -> MFMA-B fragment order bf16 + bias tiles; zero cnt ----
// Tile T = d0*4 + ht covers GEMM cols n = (ht*16 + c)*64 + d0, c=0..15.
// B frag for mfma_f32_16x16x32_bf16: lane l holds B[k=(l>>4)*8+j][col=l&15], j=0..7.
__global__ __launch_bounds__(256) void prep_kernel(
    const float* __restrict__ We, const float* __restrict__ be,
    __bf16* __restrict__ Wp, float* __restrict__ bp, int* __restrict__ cnt_i) {
  int tid = blockIdx.x * 256 + threadIdx.x;       // 16384 packers
  if (tid < NDST) cnt_i[tid] = 0;                 // zero histogram (hist runs in edge dispatch)
  int T = tid >> 6, l = tid & 63;
  int d0 = T >> 2, ht = T & 3;
  int c = l & 15, kg = l >> 4;
  int ncol = (ht * 16 + c) * 64 + d0;
  bf16x8 v;
#pragma unroll
  for (int j = 0; j < 8; ++j) v[j] = (__bf16)We[(kg * 8 + j) * 4096 + ncol];
  *reinterpret_cast<bf16x8*>(Wp + tid * 8) = v;
  if (l < 16) bp[T * 16 + l] = be[(ht * 16 + l) * 64 + d0];
}

// ---- parallel exclusive scan over 8192 bins (one block, shfl + LDS) ----
__global__ __launch_bounds__(256) void scan_kernel(const int* __restrict__ cnt_i,
                                                   int* __restrict__ off,
                                                   int* __restrict__ cursor) {
  __shared__ int wsum[4];
  const int t = threadIdx.x;
  const int lane = t & 63, w = t >> 6;
  int vals[32];
  const int4* cp = (const int4*)(cnt_i + t * 32);
#pragma unroll
  for (int i = 0; i < 8; ++i) {
    int4 v = cp[i];
    vals[i * 4 + 0] = v.x; vals[i * 4 + 1] = v.y;
    vals[i * 4 + 2] = v.z; vals[i * 4 + 3] = v.w;
  }
  int loc[32];
  int s = 0;
#pragma unroll
  for (int i = 0; i < 32; ++i) { loc[i] = s; s += vals[i]; }
  int inc = s;
#pragma unroll
  for (int d = 1; d < 64; d <<= 1) {
    int n = __shfl_up(inc, d, 64);
    if (lane >= d) inc += n;
  }
  if (lane == 63) wsum[w] = inc;
  __syncthreads();
  int base = inc - s;
#pragma unroll
  for (int i = 0; i < 4; ++i)
    if (i < w) base += wsum[i];
#pragma unroll
  for (int i = 0; i < 32; ++i) {
    int v = base + loc[i];
    off[t * 32 + i] = v;
    cursor[t * 32 + i] = v;
  }
  if (t == 255) off[8192] = E_TOT;
}

// ---- fill: scatter edge ids into CSR order (int atomics on cursor) ----
__global__ void fill_kernel(const int* __restrict__ dst, int* __restrict__ cursor,
                            int* __restrict__ eid) {
  int e = blockIdx.x * 256 + threadIdx.x;
  int slot = atomicAdd(&cursor[dst[e]], 1);
  eid[slot] = e;
}

// ---- edge compute (R12 proven, pipelined epilogue): m[e][h] = sum_d relu(ef@We+be)*h_src ----
// 4 waves, 64 edges; wave w owns h-quadrant ht=w; grid 1024; hist fused.
__global__ __launch_bounds__(256, 2) void edge9_kernel(
    const float* __restrict__ nf, const float* __restrict__ ef,
    const int* __restrict__ src, const int* __restrict__ dst,
    const __bf16* __restrict__ Wp, const float* __restrict__ bp,
    float* __restrict__ m, int* __restrict__ cnt_i) {
  __shared__ float hs[64 * EPF];   // transposed f32 h_src: hs[d][e_local], 17.4 KB
  const int t = threadIdx.x;
  const int eblk = blockIdx.x << 6;

  // stage h_src transposed: thread t -> edge el=t&63, d-quarter q=t>>6 (16 d each)
  {
    const int el = t & 63, q = t >> 6;
    const int srow = src[eblk + el];
    const f32x4* nfr = (const f32x4*)(nf + (srow << 6) + (q << 4));
#pragma unroll
    for (int i = 0; i < 4; ++i) {
      f32x4 v = nfr[i];
      const int dbase = (q << 4) + i * 4;
      hs[(dbase + 0) * EPF + el] = v[0];
      hs[(dbase + 1) * EPF + el] = v[1];
      hs[(dbase + 2) * EPF + el] = v[2];
      hs[(dbase + 3) * EPF + el] = v[3];
    }
  }

  // fused dst histogram (cnt_i zeroed by prep)
  if (t < 64) atomicAdd(&cnt_i[dst[eblk + t]], 1);

  const int w = t >> 6, l = t & 63;
  const int c = l & 15, g = l >> 4;

  // A fragments: lane holds A[row=c][k=g*8+j] for 4 edge-groups of 16
  bf16x8 afr[4];
#pragma unroll
  for (int as = 0; as < 4; ++as) {
    const int e = eblk + as * 16 + c;
    const f32x4* p = (const f32x4*)(ef + (e << 5) + (g << 3));
    f32x4 v0 = p[0], v1 = p[1];
    bf16x8 a;
    a[0] = (__bf16)v0[0]; a[1] = (__bf16)v0[1]; a[2] = (__bf16)v0[2]; a[3] = (__bf16)v0[3];
    a[4] = (__bf16)v1[0]; a[5] = (__bf16)v1[1]; a[6] = (__bf16)v1[2]; a[7] = (__bf16)v1[3];
    afr[as] = a;
  }

  f32x2 accA[4], accB[4];   // [as]; rows (g*4+0,g*4+1) / (g*4+2,g*4+3)
#pragma unroll
  for (int i = 0; i < 4; ++i) {
    accA[i][0] = 0.f; accA[i][1] = 0.f;
    accB[i][0] = 0.f; accB[i][1] = 0.f;
  }

  const bf16x8* WpV = (const bf16x8*)Wp;

  // B/bias depth-2 prefetch regs
  bf16x8 bfrA = WpV[(0 * 4 + w) * 64 + l];
  float  bvA  = bp[(0 * 4 + w) * 16 + c];
  bf16x8 bfrB = WpV[(1 * 4 + w) * 64 + l];
  float  bvB  = bp[(1 * 4 + w) * 16 + c];

  __syncthreads();   // hs ready

  const int hoff = g << 2;   // + as*16 per fragment

  // pipeline register sets
  f32x4 tE0, tE1, tE2, tE3, tO0, tO1, tO2, tO3;   // MFMA results (even/odd sections)
  f32x4 hE0, hE1, hE2, hE3, hO0, hO1, hO2, hO3;   // matching h_src vectors

#define ISSUE_SET(T0, T1, T2, T3, BFR, BV)                                         \
  {                                                                                \
    const f32x4 cb = {BV, BV, BV, BV};                                             \
    T0 = __builtin_amdgcn_mfma_f32_16x16x32_bf16(afr[0], BFR, cb, 0, 0, 0);        \
    T1 = __builtin_amdgcn_mfma_f32_16x16x32_bf16(afr[1], BFR, cb, 0, 0, 0);        \
    T2 = __builtin_amdgcn_mfma_f32_16x16x32_bf16(afr[2], BFR, cb, 0, 0, 0);        \
    T3 = __builtin_amdgcn_mfma_f32_16x16x32_bf16(afr[3], BFR, cb, 0, 0, 0);        \
  }

#define LOADHV_SET(H0, H1, H2, H3, D0)                                             \
  {                                                                                \
    H0 = *(const f32x4*)&hs[(D0) * EPF +  0 + hoff];                               \
    H1 = *(const f32x4*)&hs[(D0) * EPF + 16 + hoff];                               \
    H2 = *(const f32x4*)&hs[(D0) * EPF + 32 + hoff];                               \
    H3 = *(const f32x4*)&hs[(D0) * EPF + 48 + hoff];                               \
  }

#define CONSUME_ONE(AS, TT, HH)                                                    \
  {                                                                                \
    f32x2 p, hl, hh;                                                               \
    hl = __builtin_shufflevector(HH, HH, 0, 1);                                    \
    hh = __builtin_shufflevector(HH, HH, 2, 3);                                    \
    p[0] = fmaxf(TT[0], 0.f); p[1] = fmaxf(TT[1], 0.f);                            \
    asm("v_pk_fma_f32 %0, %1, %2, %0" : "+v"(accA[AS]) : "v"(p), "v"(hl));         \
    p[0] = fmaxf(TT[2], 0.f); p[1] = fmaxf(TT[3], 0.f);                            \
    asm("v_pk_fma_f32 %0, %1, %2, %0" : "+v"(accB[AS]) : "v"(p), "v"(hh));         \
  }

#define CONSUME_SET(T0, T1, T2, T3, H0, H1, H2, H3)                                \
  CONSUME_ONE(0, T0, H0) CONSUME_ONE(1, T1, H1)                                    \
  CONSUME_ONE(2, T2, H2) CONSUME_ONE(3, T3, H3)

  // prologue: issue sections d0=0 (E) and d0=1 (O); no consumption yet
  ISSUE_SET(tE0, tE1, tE2, tE3, bfrA, bvA)
  LOADHV_SET(hE0, hE1, hE2, hE3, 0)
  bfrA = WpV[(2 * 4 + w) * 64 + l];
  bvA  = bp[(2 * 4 + w) * 16 + c];
  ISSUE_SET(tO0, tO1, tO2, tO3, bfrB, bvB)
  LOADHV_SET(hO0, hO1, hO2, hO3, 1)
  bfrB = WpV[(3 * 4 + w) * 64 + l];
  bvB  = bp[(3 * 4 + w) * 16 + c];

#pragma unroll 4
  for (int d0 = 2; d0 < 64; d0 += 2) {
    // consume E (d0-2), reissue E (d0)
    CONSUME_SET(tE0, tE1, tE2, tE3, hE0, hE1, hE2, hE3)
    ISSUE_SET(tE0, tE1, tE2, tE3, bfrA, bvA)
    LOADHV_SET(hE0, hE1, hE2, hE3, d0)
    if (d0 + 2 < 64) {
      bfrA = WpV[((d0 + 2) * 4 + w) * 64 + l];
      bvA  = bp[((d0 + 2) * 4 + w) * 16 + c];
    }
    // consume O (d0-1), reissue O (d0+1)
    CONSUME_SET(tO0, tO1, tO2, tO3, hO0, hO1, hO2, hO3)
    ISSUE_SET(tO0, tO1, tO2, tO3, bfrB, bvB)
    LOADHV_SET(hO0, hO1, hO2, hO3, d0 + 1)
    if (d0 + 3 < 64) {
      bfrB = WpV[((d0 + 3) * 4 + w) * 64 + l];
      bvB  = bp[((d0 + 3) * 4 + w) * 16 + c];
    }
  }

  // epilogue: consume last two sections (d0=62 E, d0=63 O)
  CONSUME_SET(tE0, tE1, tE2, tE3, hE0, hE1, hE2, hE3)
  CONSUME_SET(tO0, tO1, tO2, tO3, hO0, hO1, hO2, hO3)

#undef ISSUE_SET
#undef LOADHV_SET
#undef CONSUME_ONE
#undef CONSUME_SET

  // stores: per (as,row): 16 lanes x 4B = 64B segments
  const int hbase = (w << 4) + c;
#pragma unroll
  for (int as = 0; as < 4; ++as) {
    const int ebase = eblk + as * 16 + (g << 2);
    m[((ebase + 0) << 6) + hbase] = accA[as][0];
    m[((ebase + 1) << 6) + hbase] = accA[as][1];
    m[((ebase + 2) << 6) + hbase] = accB[as][0];
    m[((ebase + 3) << 6) + hbase] = accB[as][1];
  }
}

// ---- final: gather-mean per dst (CSR) fused with out = relu(concat@Wn + bn) ----
__global__ __launch_bounds__(256) void final5_kernel(
    const float* __restrict__ nf, const float* __restrict__ m,
    const int* __restrict__ off, const int* __restrict__ eid,
    const float* __restrict__ Wn, const float* __restrict__ bn,
    float* __restrict__ out) {
  __shared__ float wn_s[128 * 64];   // 32 KB
  __shared__ float hn_s[8 * 64];     // 2 KB
  const int t = threadIdx.x;
#pragma unroll
  for (int i = 0; i < 8; ++i)
    ((f32x4*)wn_s)[i * 256 + t] = ((const f32x4*)Wn)[i * 256 + t];

  const int w = t >> 6, h = t & 63;
  const int row0 = blockIdx.x * 8 + w * 2;

#pragma unroll
  for (int i = 0; i < 2; ++i) {
    const int d = row0 + i;
    const int lo = off[d], hi = off[d + 1];
    float a0 = 0.f, a1 = 0.f;
    int j = lo;
    for (; j + 2 <= hi; j += 2) {
      const int e0 = eid[j], e1 = eid[j + 1];
      a0 += m[(e0 << 6) + h];
      a1 += m[(e1 << 6) + h];
    }
    if (j < hi) a0 += m[(eid[j] << 6) + h];
    const float a = a0 + a1;
    hn_s[(w * 2 + i) * 64 + h] = (hi > lo) ? a * (1.f / (float)(hi - lo)) : 0.f;
  }
  __syncthreads();

  const float bv = bn[h];
  float acc[2] = {bv, bv};
#pragma unroll 4
  for (int k = 0; k < 64; ++k) {
    const float wv = wn_s[k * 64 + h];
#pragma unroll
    for (int i = 0; i < 2; ++i)
      acc[i] = fmaf(nf[(row0 + i) * 64 + k], wv, acc[i]);
  }
#pragma unroll 4
  for (int k = 0; k < 64; ++k) {
    const float wv = wn_s[(64 + k) * 64 + h];
#pragma unroll
    for (int i = 0; i < 2; ++i)
      acc[i] = fmaf(hn_s[(w * 2 + i) * 64 + k], wv, acc[i]);
  }
#pragma unroll
  for (int i = 0; i < 2; ++i)
    out[(row0 + i) * 64 + h] = fmaxf(acc[i], 0.f);
}

// ================= atomic fallback (R3, proven) =================

__global__ __launch_bounds__(256, 4) void edge_kernel(
    const float* __restrict__ nf, const float* __restrict__ ef,
    const int* __restrict__ src, const int* __restrict__ dst,
    const __bf16* __restrict__ Wp, const float* __restrict__ bp,
    float* __restrict__ msum, float* __restrict__ cnt_g) {
  __shared__ __bf16 hs[64 * EPW];
  const int t = threadIdx.x;
  const int eblk = blockIdx.x << 6;
  {
    const int el = t & 63, q = t >> 6;
    const int srow = src[eblk + el];
    const f32x4* nfr = (const f32x4*)(nf + (srow << 6) + (q << 4));
#pragma unroll
    for (int i = 0; i < 4; ++i) {
      f32x4 v = nfr[i];
      const int dbase = (q << 4) + i * 4;
      hs[(dbase + 0) * EPW + el] = (__bf16)v[0];
      hs[(dbase + 1) * EPW + el] = (__bf16)v[1];
      hs[(dbase + 2) * EPW + el] = (__bf16)v[2];
      hs[(dbase + 3) * EPW + el] = (__bf16)v[3];
    }
  }
  const int w = t >> 6, l = t & 63, c = l & 15, g = l >> 4;
  bf16x8 afr[4];
#pragma unroll
  for (int as = 0; as < 4; ++as) {
    const int e = eblk + as * 16 + c;
    const f32x4* p = (const f32x4*)(ef + (e << 5) + (g << 3));
    f32x4 v0 = p[0], v1 = p[1];
    bf16x8 a;
    a[0] = (__bf16)v0[0]; a[1] = (__bf16)v0[1]; a[2] = (__bf16)v0[2]; a[3] = (__bf16)v0[3];
    a[4] = (__bf16)v1[0]; a[5] = (__bf16)v1[1]; a[6] = (__bf16)v1[2]; a[7] = (__bf16)v1[3];
    afr[as] = a;
  }
  __syncthreads();
  f32x4 acc[4];
#pragma unroll
  for (int i = 0; i < 4; ++i) { acc[i][0]=0.f; acc[i][1]=0.f; acc[i][2]=0.f; acc[i][3]=0.f; }
  const bf16x8* WpV = (const bf16x8*)Wp;
  const f32x4 zero = {0.f, 0.f, 0.f, 0.f};
#pragma unroll 4
  for (int d0 = 0; d0 < 64; ++d0) {
    const int T = d0 * 4 + w;
    const bf16x8 bfr = WpV[T * 64 + l];
    const float bv = bp[T * 16 + c];
    const f32x4 cb = {bv, bv, bv, bv};
#pragma unroll
    for (int as = 0; as < 4; ++as) {
      const bf16x4 hv = *(const bf16x4*)&hs[d0 * EPW + as * 16 + (g << 2)];
      const f32x4 hvf = {(float)hv[0], (float)hv[1], (float)hv[2], (float)hv[3]};
      f32x4 tmp = __builtin_amdgcn_mfma_f32_16x16x32_bf16(afr[as], bfr, cb, 0, 0, 0);
      tmp = __builtin_elementwise_max(tmp, zero);
      acc[as] = tmp * hvf + acc[as];
    }
  }
#pragma unroll
  for (int as = 0; as < 4; ++as)
#pragma unroll
    for (int r = 0; r < 4; ++r) {
      const int e = eblk + as * 16 + (g << 2) + r;
      const int dd = dst[e];
      unsafeAtomicAdd(msum + (dd << 6) + (w << 4) + c, acc[as][r]);
      if (w == 0 && c == 0) unsafeAtomicAdd(cnt_g + dd, 1.0f);
    }
}

__global__ __launch_bounds__(256) void final_kernel(
    const float* __restrict__ nf, const float* __restrict__ msum,
    const float* __restrict__ cnt, const float* __restrict__ Wn,
    const float* __restrict__ bn, float* __restrict__ out) {
  __shared__ float wn_s[128 * 64];
  const int t = threadIdx.x;
#pragma unroll
  for (int i = 0; i < 8; ++i)
    ((f32x4*)wn_s)[i * 256 + t] = ((const f32x4*)Wn)[i * 256 + t];
  __syncthreads();
  const int w = t >> 6, h = t & 63;
  const int row0 = blockIdx.x * 16 + w * 4;
  const float bv = bn[h];
  float acc[4] = {bv, bv, bv, bv};
  float s[4];
#pragma unroll
  for (int i = 0; i < 4; ++i) {
    const float cv = cnt[row0 + i];
    s[i] = cv > 0.f ? 1.f / cv : 0.f;
  }
#pragma unroll 4
  for (int k = 0; k < 64; ++k) {
    const float wv = wn_s[k * 64 + h];
#pragma unroll
    for (int i = 0; i < 4; ++i) acc[i] = fmaf(nf[(row0 + i) * 64 + k], wv, acc[i]);
  }
#pragma unroll 4
  for (int k = 0; k < 64; ++k) {
    const float wv = wn_s[(64 + k) * 64 + h];
#pragma unroll
    for (int i = 0; i < 4; ++i) acc[i] = fmaf(msum[(row0 + i) * 64 + k] * s[i], wv, acc[i]);
  }
#pragma unroll
  for (int i = 0; i < 4; ++i) out[(row0 + i) * 64 + h] = fmaxf(acc[i], 0.f);
}

// ================= launcher =================

extern "C" void kernel_launch(void* const* d_in, const int* in_sizes, int n_in,
                              void* d_out, int out_size, void* d_ws, size_t ws_size,
                              hipStream_t stream) {
  const float* nf  = (const float*)d_in[0];
  const float* ef  = (const float*)d_in[1];
  const int*   src = (const int*)d_in[2];
  const int*   dst = (const int*)d_in[3];
  const float* We  = (const float*)d_in[4];
  const float* be  = (const float*)d_in[5];
  const float* Wn  = (const float*)d_in[6];
  const float* bn  = (const float*)d_in[7];
  float* out = (float*)d_out;
  char* ws = (char*)d_ws;

  const size_t MB = 16777216;  // m buffer bytes (E*64*4)
  const size_t T_OFF    = MB;
  const size_t T_CURSOR = T_OFF + 36864;
  const size_t T_CNTI   = T_CURSOR + 32768;
  const size_t T_EID    = T_CNTI + 32768;
  const size_t T_WP     = T_EID + 262144;
  const size_t T_BP     = T_WP + 262144;
  const size_t NEED     = T_BP + 16384;      // ~17.4 MB

  if (ws_size >= NEED) {
    float*  m      = (float*)ws;
    int*    off    = (int*)(ws + T_OFF);
    int*    cursor = (int*)(ws + T_CURSOR);
    int*    cnt_i  = (int*)(ws + T_CNTI);
    int*    eid    = (int*)(ws + T_EID);
    __bf16* Wp     = (__bf16*)(ws + T_WP);
    float*  bp     = (float*)(ws + T_BP);

    prep_kernel<<<64, 256, 0, stream>>>(We, be, Wp, bp, cnt_i);
    edge9_kernel<<<E_TOT / 64, 256, 0, stream>>>(nf, ef, src, dst, Wp, bp, m, cnt_i);
    scan_kernel<<<1, 256, 0, stream>>>(cnt_i, off, cursor);
    fill_kernel<<<E_TOT / 256, 256, 0, stream>>>(dst, cursor, eid);
    final5_kernel<<<NDST / 8, 256, 0, stream>>>(nf, m, off, eid, Wn, bn, out);
  } else {
    // atomic fallback
    float* msum = (float*)ws;
    float* cnt  = (float*)(ws + 2097152);
    const size_t need = 2097152 + 32768 + 262144 + 16384;
    __bf16* Wp;
    float*  bp;
    if (ws_size >= need) {
      Wp = (__bf16*)(ws + 2097152 + 32768);
      bp = (float*)(ws + 2097152 + 32768 + 262144);
    } else {
      Wp = (__bf16*)d_out;
      bp = (float*)((char*)d_out + 262144);
    }
    hipMemsetAsync(msum, 0, 2097152 + 32768, stream);
    prep_kernel<<<64, 256, 0, stream>>>(We, be, Wp, bp, (int*)cnt);
    edge_kernel<<<E_TOT / 64, 256, 0, stream>>>(nf, ef, src, dst, Wp, bp, msum, cnt);
    final_kernel<<<NDST / 16, 256, 0, stream>>>(nf, msum, cnt, Wn, bn, out);
  }
}

// Round 15
// 72.914 us; speedup vs baseline: 2.0917x; 1.0254x over previous
//
#include <hip/hip_runtime.h>

// ECConv: out = relu(concat(nf[:8192], mean_seg(relu(EF@We+be).reshape(E,64,64) @ h_src)) @ Wn + bn)
// Sizes: E=65536, N_SRC=32768, N_DST=8192, EDGE_IN=32, NODE_IN=64, HIDDEN=64
// R15: COMPILER-PROOF pipeline. R12's E/O software pipeline was collapsed by regalloc
//      (VGPR 36 tell). Enforcement: (1) CONSUME pk_fma asm made volatile (orders all
//      consumes), (2) empty volatile "+v" touch on each tmp set right after ISSUE
//      (no instruction emitted -> no stall; pins MFMAs before the volatile chain).
//      Chain per section: issue(E,d0) -> touch(tE) -> consume(O,d0-1) [8 volatile
//      pk_fma + 4 MFMAs + prefetch] -> consume(E,d0) => ~60-80cyc cover per tmp set.
//      Math/memory identical to R14 -> deterministic, correctness-safe.
// Lessons: R2 fp32 atomics memory-side. R4 serial scan 20us. R5/R9 spills (WRITE>>payload).
//      R6 sequential dispatches don't stack. R10 loads never the binder. R11 ablation:
//      21.3us LDS-stream base + ~25us MFMA->VALU hazard. R12 compiler collapses source
//      SWP silently (VGPR tell). R13 unexplained nondeterminism = revert, park.

typedef float f32x4 __attribute__((ext_vector_type(4)));
typedef float f32x2 __attribute__((ext_vector_type(2)));
typedef __bf16 bf16x8 __attribute__((ext_vector_type(8)));
typedef __bf16 bf16x4 __attribute__((ext_vector_type(4)));

#define E_TOT   65536
#define NDST    8192
#define EPW     72    // bf16 hs pad (atomic-fallback kernel)
#define EPF     68    // f32 hs pad (fast kernel)

// ---- prep: pack We (fp32 [32][4096]) -> MFMA-B fragment order bf16 + bias tiles; zero cnt ----
// Tile T = d0*4 + ht covers GEMM cols n = (ht*16 + c)*64 + d0, c=0..15.
// B frag for mfma_f32_16x16x32_bf16: lane l holds B[k=(l>>4)*8+j][col=l&15], j=0..7.
__global__ __launch_bounds__(256) void prep_kernel(
    const float* __restrict__ We, const float* __restrict__ be,
    __bf16* __restrict__ Wp, float* __restrict__ bp, int* __restrict__ cnt_i) {
  int tid = blockIdx.x * 256 + threadIdx.x;       // 16384 packers
  if (tid < NDST) cnt_i[tid] = 0;                 // zero histogram (hist runs in edge dispatch)
  int T = tid >> 6, l = tid & 63;
  int d0 = T >> 2, ht = T & 3;
  int c = l & 15, kg = l >> 4;
  int ncol = (ht * 16 + c) * 64 + d0;
  bf16x8 v;
#pragma unroll
  for (int j = 0; j < 8; ++j) v[j] = (__bf16)We[(kg * 8 + j) * 4096 + ncol];
  *reinterpret_cast<bf16x8*>(Wp + tid * 8) = v;
  if (l < 16) bp[T * 16 + l] = be[(ht * 16 + l) * 64 + d0];
}

// ---- parallel exclusive scan over 8192 bins (one block, shfl + LDS) ----
__global__ __launch_bounds__(256) void scan_kernel(const int* __restrict__ cnt_i,
                                                   int* __restrict__ off,
                                                   int* __restrict__ cursor) {
  __shared__ int wsum[4];
  const int t = threadIdx.x;
  const int lane = t & 63, w = t >> 6;
  int vals[32];
  const int4* cp = (const int4*)(cnt_i + t * 32);
#pragma unroll
  for (int i = 0; i < 8; ++i) {
    int4 v = cp[i];
    vals[i * 4 + 0] = v.x; vals[i * 4 + 1] = v.y;
    vals[i * 4 + 2] = v.z; vals[i * 4 + 3] = v.w;
  }
  int loc[32];
  int s = 0;
#pragma unroll
  for (int i = 0; i < 32; ++i) { loc[i] = s; s += vals[i]; }
  int inc = s;
#pragma unroll
  for (int d = 1; d < 64; d <<= 1) {
    int n = __shfl_up(inc, d, 64);
    if (lane >= d) inc += n;
  }
  if (lane == 63) wsum[w] = inc;
  __syncthreads();
  int base = inc - s;
#pragma unroll
  for (int i = 0; i < 4; ++i)
    if (i < w) base += wsum[i];
#pragma unroll
  for (int i = 0; i < 32; ++i) {
    int v = base + loc[i];
    off[t * 32 + i] = v;
    cursor[t * 32 + i] = v;
  }
  if (t == 255) off[8192] = E_TOT;
}

// ---- fill: scatter edge ids into CSR order (int atomics on cursor) ----
__global__ void fill_kernel(const int* __restrict__ dst, int* __restrict__ cursor,
                            int* __restrict__ eid) {
  int e = blockIdx.x * 256 + threadIdx.x;
  int slot = atomicAdd(&cursor[dst[e]], 1);
  eid[slot] = e;
}

// ---- edge compute (enforced pipelined epilogue): m[e][h] = sum_d relu(ef@We+be)*h_src ----
// 4 waves, 64 edges; wave w owns h-quadrant ht=w; grid 1024; hist fused.
__global__ __launch_bounds__(256, 2) void edge11_kernel(
    const float* __restrict__ nf, const float* __restrict__ ef,
    const int* __restrict__ src, const int* __restrict__ dst,
    const __bf16* __restrict__ Wp, const float* __restrict__ bp,
    float* __restrict__ m, int* __restrict__ cnt_i) {
  __shared__ float hs[64 * EPF];   // transposed f32 h_src: hs[d][e_local], 17.4 KB
  const int t = threadIdx.x;
  const int eblk = blockIdx.x << 6;

  // stage h_src transposed: thread t -> edge el=t&63, d-quarter q=t>>6 (16 d each)
  {
    const int el = t & 63, q = t >> 6;
    const int srow = src[eblk + el];
    const f32x4* nfr = (const f32x4*)(nf + (srow << 6) + (q << 4));
#pragma unroll
    for (int i = 0; i < 4; ++i) {
      f32x4 v = nfr[i];
      const int dbase = (q << 4) + i * 4;
      hs[(dbase + 0) * EPF + el] = v[0];
      hs[(dbase + 1) * EPF + el] = v[1];
      hs[(dbase + 2) * EPF + el] = v[2];
      hs[(dbase + 3) * EPF + el] = v[3];
    }
  }

  // fused dst histogram (cnt_i zeroed by prep)
  if (t < 64) atomicAdd(&cnt_i[dst[eblk + t]], 1);

  const int w = t >> 6, l = t & 63;
  const int c = l & 15, g = l >> 4;

  // A fragments: lane holds A[row=c][k=g*8+j] for 4 edge-groups of 16
  bf16x8 afr[4];
#pragma unroll
  for (int as = 0; as < 4; ++as) {
    const int e = eblk + as * 16 + c;
    const f32x4* p = (const f32x4*)(ef + (e << 5) + (g << 3));
    f32x4 v0 = p[0], v1 = p[1];
    bf16x8 a;
    a[0] = (__bf16)v0[0]; a[1] = (__bf16)v0[1]; a[2] = (__bf16)v0[2]; a[3] = (__bf16)v0[3];
    a[4] = (__bf16)v1[0]; a[5] = (__bf16)v1[1]; a[6] = (__bf16)v1[2]; a[7] = (__bf16)v1[3];
    afr[as] = a;
  }

  f32x2 accA[4], accB[4];   // [as]; rows (g*4+0,g*4+1) / (g*4+2,g*4+3)
#pragma unroll
  for (int i = 0; i < 4; ++i) {
    accA[i][0] = 0.f; accA[i][1] = 0.f;
    accB[i][0] = 0.f; accB[i][1] = 0.f;
  }

  const bf16x8* WpV = (const bf16x8*)Wp;

  // B/bias depth-2 prefetch regs
  bf16x8 bfrA = WpV[(0 * 4 + w) * 64 + l];
  float  bvA  = bp[(0 * 4 + w) * 16 + c];
  bf16x8 bfrB = WpV[(1 * 4 + w) * 64 + l];
  float  bvB  = bp[(1 * 4 + w) * 16 + c];

  __syncthreads();   // hs ready

  const int hoff = g << 2;   // + as*16 per fragment

  // pipeline register sets
  f32x4 tE0, tE1, tE2, tE3, tO0, tO1, tO2, tO3;   // MFMA results (even/odd sections)
  f32x4 hE0, hE1, hE2, hE3, hO0, hO1, hO2, hO3;   // matching h_src vectors

#define ISSUE_SET(T0, T1, T2, T3, BFR, BV)                                         \
  {                                                                                \
    const f32x4 cb = {BV, BV, BV, BV};                                             \
    T0 = __builtin_amdgcn_mfma_f32_16x16x32_bf16(afr[0], BFR, cb, 0, 0, 0);        \
    T1 = __builtin_amdgcn_mfma_f32_16x16x32_bf16(afr[1], BFR, cb, 0, 0, 0);        \
    T2 = __builtin_amdgcn_mfma_f32_16x16x32_bf16(afr[2], BFR, cb, 0, 0, 0);        \
    T3 = __builtin_amdgcn_mfma_f32_16x16x32_bf16(afr[3], BFR, cb, 0, 0, 0);        \
    asm volatile("" : "+v"(T0), "+v"(T1), "+v"(T2), "+v"(T3));                     \
  }

#define LOADHV_SET(H0, H1, H2, H3, D0)                                             \
  {                                                                                \
    H0 = *(const f32x4*)&hs[(D0) * EPF +  0 + hoff];                               \
    H1 = *(const f32x4*)&hs[(D0) * EPF + 16 + hoff];                               \
    H2 = *(const f32x4*)&hs[(D0) * EPF + 32 + hoff];                               \
    H3 = *(const f32x4*)&hs[(D0) * EPF + 48 + hoff];                               \
  }

#define CONSUME_ONE(AS, TT, HH)                                                    \
  {                                                                                \
    f32x2 p, hl, hh;                                                               \
    hl = __builtin_shufflevector(HH, HH, 0, 1);                                    \
    hh = __builtin_shufflevector(HH, HH, 2, 3);                                    \
    p[0] = fmaxf(TT[0], 0.f); p[1] = fmaxf(TT[1], 0.f);                            \
    asm volatile("v_pk_fma_f32 %0, %1, %2, %0" : "+v"(accA[AS]) : "v"(p), "v"(hl));\
    p[0] = fmaxf(TT[2], 0.f); p[1] = fmaxf(TT[3], 0.f);                            \
    asm volatile("v_pk_fma_f32 %0, %1, %2, %0" : "+v"(accB[AS]) : "v"(p), "v"(hh));\
  }

#define CONSUME_SET(T0, T1, T2, T3, H0, H1, H2, H3)                                \
  CONSUME_ONE(0, T0, H0) CONSUME_ONE(1, T1, H1)                                    \
  CONSUME_ONE(2, T2, H2) CONSUME_ONE(3, T3, H3)

  // prologue: issue sections d0=0 (E) and d0=1 (O); no consumption yet
  ISSUE_SET(tE0, tE1, tE2, tE3, bfrA, bvA)
  LOADHV_SET(hE0, hE1, hE2, hE3, 0)
  bfrA = WpV[(2 * 4 + w) * 64 + l];
  bvA  = bp[(2 * 4 + w) * 16 + c];
  ISSUE_SET(tO0, tO1, tO2, tO3, bfrB, bvB)
  LOADHV_SET(hO0, hO1, hO2, hO3, 1)
  bfrB = WpV[(3 * 4 + w) * 64 + l];
  bvB  = bp[(3 * 4 + w) * 16 + c];

#pragma unroll 4
  for (int d0 = 2; d0 < 64; d0 += 2) {
    // consume E (d0-2), reissue E (d0)
    CONSUME_SET(tE0, tE1, tE2, tE3, hE0, hE1, hE2, hE3)
    ISSUE_SET(tE0, tE1, tE2, tE3, bfrA, bvA)
    LOADHV_SET(hE0, hE1, hE2, hE3, d0)
    if (d0 + 2 < 64) {
      bfrA = WpV[((d0 + 2) * 4 + w) * 64 + l];
      bvA  = bp[((d0 + 2) * 4 + w) * 16 + c];
    }
    // consume O (d0-1), reissue O (d0+1)
    CONSUME_SET(tO0, tO1, tO2, tO3, hO0, hO1, hO2, hO3)
    ISSUE_SET(tO0, tO1, tO2, tO3, bfrB, bvB)
    LOADHV_SET(hO0, hO1, hO2, hO3, d0 + 1)
    if (d0 + 3 < 64) {
      bfrB = WpV[((d0 + 3) * 4 + w) * 64 + l];
      bvB  = bp[((d0 + 3) * 4 + w) * 16 + c];
    }
  }

  // epilogue: consume last two sections (d0=62 E, d0=63 O)
  CONSUME_SET(tE0, tE1, tE2, tE3, hE0, hE1, hE2, hE3)
  CONSUME_SET(tO0, tO1, tO2, tO3, hO0, hO1, hO2, hO3)

#undef ISSUE_SET
#undef LOADHV_SET
#undef CONSUME_ONE
#undef CONSUME_SET

  // stores: per (as,row): 16 lanes x 4B = 64B segments
  const int hbase = (w << 4) + c;
#pragma unroll
  for (int as = 0; as < 4; ++as) {
    const int ebase = eblk + as * 16 + (g << 2);
    m[((ebase + 0) << 6) + hbase] = accA[as][0];
    m[((ebase + 1) << 6) + hbase] = accA[as][1];
    m[((ebase + 2) << 6) + hbase] = accB[as][0];
    m[((ebase + 3) << 6) + hbase] = accB[as][1];
  }
}

// ---- final: gather-mean per dst (CSR) fused with out = relu(concat@Wn + bn) ----
__global__ __launch_bounds__(256) void final5_kernel(
    const float* __restrict__ nf, const float* __restrict__ m,
    const int* __restrict__ off, const int* __restrict__ eid,
    const float* __restrict__ Wn, const float* __restrict__ bn,
    float* __restrict__ out) {
  __shared__ float wn_s[128 * 64];   // 32 KB
  __shared__ float hn_s[8 * 64];     // 2 KB
  const int t = threadIdx.x;
#pragma unroll
  for (int i = 0; i < 8; ++i)
    ((f32x4*)wn_s)[i * 256 + t] = ((const f32x4*)Wn)[i * 256 + t];

  const int w = t >> 6, h = t & 63;
  const int row0 = blockIdx.x * 8 + w * 2;

#pragma unroll
  for (int i = 0; i < 2; ++i) {
    const int d = row0 + i;
    const int lo = off[d], hi = off[d + 1];
    float a0 = 0.f, a1 = 0.f;
    int j = lo;
    for (; j + 2 <= hi; j += 2) {
      const int e0 = eid[j], e1 = eid[j + 1];
      a0 += m[(e0 << 6) + h];
      a1 += m[(e1 << 6) + h];
    }
    if (j < hi) a0 += m[(eid[j] << 6) + h];
    const float a = a0 + a1;
    hn_s[(w * 2 + i) * 64 + h] = (hi > lo) ? a * (1.f / (float)(hi - lo)) : 0.f;
  }
  __syncthreads();

  const float bv = bn[h];
  float acc[2] = {bv, bv};
#pragma unroll 4
  for (int k = 0; k < 64; ++k) {
    const float wv = wn_s[k * 64 + h];
#pragma unroll
    for (int i = 0; i < 2; ++i)
      acc[i] = fmaf(nf[(row0 + i) * 64 + k], wv, acc[i]);
  }
#pragma unroll 4
  for (int k = 0; k < 64; ++k) {
    const float wv = wn_s[(64 + k) * 64 + h];
#pragma unroll
    for (int i = 0; i < 2; ++i)
      acc[i] = fmaf(hn_s[(w * 2 + i) * 64 + k], wv, acc[i]);
  }
#pragma unroll
  for (int i = 0; i < 2; ++i)
    out[(row0 + i) * 64 + h] = fmaxf(acc[i], 0.f);
}

// ================= atomic fallback (R3, proven) =================

__global__ __launch_bounds__(256, 4) void edge_kernel(
    const float* __restrict__ nf, const float* __restrict__ ef,
    const int* __restrict__ src, const int* __restrict__ dst,
    const __bf16* __restrict__ Wp, const float* __restrict__ bp,
    float* __restrict__ msum, float* __restrict__ cnt_g) {
  __shared__ __bf16 hs[64 * EPW];
  const int t = threadIdx.x;
  const int eblk = blockIdx.x << 6;
  {
    const int el = t & 63, q = t >> 6;
    const int srow = src[eblk + el];
    const f32x4* nfr = (const f32x4*)(nf + (srow << 6) + (q << 4));
#pragma unroll
    for (int i = 0; i < 4; ++i) {
      f32x4 v = nfr[i];
      const int dbase = (q << 4) + i * 4;
      hs[(dbase + 0) * EPW + el] = (__bf16)v[0];
      hs[(dbase + 1) * EPW + el] = (__bf16)v[1];
      hs[(dbase + 2) * EPW + el] = (__bf16)v[2];
      hs[(dbase + 3) * EPW + el] = (__bf16)v[3];
    }
  }
  const int w = t >> 6, l = t & 63, c = l & 15, g = l >> 4;
  bf16x8 afr[4];
#pragma unroll
  for (int as = 0; as < 4; ++as) {
    const int e = eblk + as * 16 + c;
    const f32x4* p = (const f32x4*)(ef + (e << 5) + (g << 3));
    f32x4 v0 = p[0], v1 = p[1];
    bf16x8 a;
    a[0] = (__bf16)v0[0]; a[1] = (__bf16)v0[1]; a[2] = (__bf16)v0[2]; a[3] = (__bf16)v0[3];
    a[4] = (__bf16)v1[0]; a[5] = (__bf16)v1[1]; a[6] = (__bf16)v1[2]; a[7] = (__bf16)v1[3];
    afr[as] = a;
  }
  __syncthreads();
  f32x4 acc[4];
#pragma unroll
  for (int i = 0; i < 4; ++i) { acc[i][0]=0.f; acc[i][1]=0.f; acc[i][2]=0.f; acc[i][3]=0.f; }
  const bf16x8* WpV = (const bf16x8*)Wp;
  const f32x4 zero = {0.f, 0.f, 0.f, 0.f};
#pragma unroll 4
  for (int d0 = 0; d0 < 64; ++d0) {
    const int T = d0 * 4 + w;
    const bf16x8 bfr = WpV[T * 64 + l];
    const float bv = bp[T * 16 + c];
    const f32x4 cb = {bv, bv, bv, bv};
#pragma unroll
    for (int as = 0; as < 4; ++as) {
      const bf16x4 hv = *(const bf16x4*)&hs[d0 * EPW + as * 16 + (g << 2)];
      const f32x4 hvf = {(float)hv[0], (float)hv[1], (float)hv[2], (float)hv[3]};
      f32x4 tmp = __builtin_amdgcn_mfma_f32_16x16x32_bf16(afr[as], bfr, cb, 0, 0, 0);
      tmp = __builtin_elementwise_max(tmp, zero);
      acc[as] = tmp * hvf + acc[as];
    }
  }
#pragma unroll
  for (int as = 0; as < 4; ++as)
#pragma unroll
    for (int r = 0; r < 4; ++r) {
      const int e = eblk + as * 16 + (g << 2) + r;
      const int dd = dst[e];
      unsafeAtomicAdd(msum + (dd << 6) + (w << 4) + c, acc[as][r]);
      if (w == 0 && c == 0) unsafeAtomicAdd(cnt_g + dd, 1.0f);
    }
}

__global__ __launch_bounds__(256) void final_kernel(
    const float* __restrict__ nf, const float* __restrict__ msum,
    const float* __restrict__ cnt, const float* __restrict__ Wn,
    const float* __restrict__ bn, float* __restrict__ out) {
  __shared__ float wn_s[128 * 64];
  const int t = threadIdx.x;
#pragma unroll
  for (int i = 0; i < 8; ++i)
    ((f32x4*)wn_s)[i * 256 + t] = ((const f32x4*)Wn)[i * 256 + t];
  __syncthreads();
  const int w = t >> 6, h = t & 63;
  const int row0 = blockIdx.x * 16 + w * 4;
  const float bv = bn[h];
  float acc[4] = {bv, bv, bv, bv};
  float s[4];
#pragma unroll
  for (int i = 0; i < 4; ++i) {
    const float cv = cnt[row0 + i];
    s[i] = cv > 0.f ? 1.f / cv : 0.f;
  }
#pragma unroll 4
  for (int k = 0; k < 64; ++k) {
    const float wv = wn_s[k * 64 + h];
#pragma unroll
    for (int i = 0; i < 4; ++i) acc[i] = fmaf(nf[(row0 + i) * 64 + k], wv, acc[i]);
  }
#pragma unroll 4
  for (int k = 0; k < 64; ++k) {
    const float wv = wn_s[(64 + k) * 64 + h];
#pragma unroll
    for (int i = 0; i < 4; ++i) acc[i] = fmaf(msum[(row0 + i) * 64 + k] * s[i], wv, acc[i]);
  }
#pragma unroll
  for (int i = 0; i < 4; ++i) out[(row0 + i) * 64 + h] = fmaxf(acc[i], 0.f);
}

// ================= launcher =================

extern "C" void kernel_launch(void* const* d_in, const int* in_sizes, int n_in,
                              void* d_out, int out_size, void* d_ws, size_t ws_size,
                              hipStream_t stream) {
  const float* nf  = (const float*)d_in[0];
  const float* ef  = (const float*)d_in[1];
  const int*   src = (const int*)d_in[2];
  const int*   dst = (const int*)d_in[3];
  const float* We  = (const float*)d_in[4];
  const float* be  = (const float*)d_in[5];
  const float* Wn  = (const float*)d_in[6];
  const float* bn  = (const float*)d_in[7];
  float* out = (float*)d_out;
  char* ws = (char*)d_ws;

  const size_t MB = 16777216;  // m buffer bytes (E*64*4)
  const size_t T_OFF    = MB;
  const size_t T_CURSOR = T_OFF + 36864;
  const size_t T_CNTI   = T_CURSOR + 32768;
  const size_t T_EID    = T_CNTI + 32768;
  const size_t T_WP     = T_EID + 262144;
  const size_t T_BP     = T_WP + 262144;
  const size_t NEED     = T_BP + 16384;      // ~17.4 MB

  if (ws_size >= NEED) {
    float*  m      = (float*)ws;
    int*    off    = (int*)(ws + T_OFF);
    int*    cursor = (int*)(ws + T_CURSOR);
    int*    cnt_i  = (int*)(ws + T_CNTI);
    int*    eid    = (int*)(ws + T_EID);
    __bf16* Wp     = (__bf16*)(ws + T_WP);
    float*  bp     = (float*)(ws + T_BP);

    prep_kernel<<<64, 256, 0, stream>>>(We, be, Wp, bp, cnt_i);
    edge11_kernel<<<E_TOT / 64, 256, 0, stream>>>(nf, ef, src, dst, Wp, bp, m, cnt_i);
    scan_kernel<<<1, 256, 0, stream>>>(cnt_i, off, cursor);
    fill_kernel<<<E_TOT / 256, 256, 0, stream>>>(dst, cursor, eid);
    final5_kernel<<<NDST / 8, 256, 0, stream>>>(nf, m, off, eid, Wn, bn, out);
  } else {
    // atomic fallback
    float* msum = (float*)ws;
    float* cnt  = (float*)(ws + 2097152);
    const size_t need = 2097152 + 32768 + 262144 + 16384;
    __bf16* Wp;
    float*  bp;
    if (ws_size >= need) {
      Wp = (__bf16*)(ws + 2097152 + 32768);
      bp = (float*)(ws + 2097152 + 32768 + 262144);
    } else {
      Wp = (__bf16*)d_out;
      bp = (float*)((char*)d_out + 262144);
    }
    hipMemsetAsync(msum, 0, 2097152 + 32768, stream);
    prep_kernel<<<64, 256, 0, stream>>>(We, be, Wp, bp, (int*)cnt);
    edge_kernel<<<E_TOT / 64, 256, 0, stream>>>(nf, ef, src, dst, Wp, bp, msum, cnt);
    final_kernel<<<NDST / 16, 256, 0, stream>>>(nf, msum, cnt, Wn, bn, out);
  }
}